// Round 8
// baseline (459.751 us; speedup 1.0000x reference)
//
#include <hip/hip_runtime.h>

// NearestNeighborTokenizer: ids = (min_c ||x - c||^2 <= 900) ? argmin_c : -1
// x: [8192, 512] fp32, codes: [16384, 512] fp32, out: [8192] int32
//
// fp16x3 MFMA GEMM: x,c scaled by 16, split into fp16 hi+lo planes,
// pre-swizzled in global memory into MFMA fragment order. dot =
// (hh + hl + lh)/256 in one fp32 acc. score = ||c||^2 - 2*dot.
//
// R13: A-direct-to-registers with one-iteration prefetch, on the R12
// schedule (depth-2 B prefetch + single barrier/iter, 298us, MfmaUtil
// 64). R12 left ~1650 cyc/iter over the 3954-cyc MFMA floor; a third
// of the LDS reads and half the stage writes are the A-side, and A is
// a 512KB L2-resident slab. R8 proved A-direct addressing correct but
// consumed A with zero runway (exposed L2 latency). Here A(it+1) loads
// issue right after stage(it+1) and are consumed NEXT iteration
// (~5000cyc runway, drained by the already-free top vmcnt(0)). LDS is
// B-only (2x32KB); LDS demand ~1920cyc < MFMA 3954. Register budget:
// A-next (+32 VGPR) paid for by moving the running argmin (mv/mi, 32
// VGPR) to the R9-verified 4KB LDS single-owner table. Explicit 2x
// loop unroll gives static A-reg double buffering (no dyn indexing).

#define NTOK   8192
#define NCODES 16384
#define DDIM   512
#define NCHUNK 8
#define CHUNK  2048
#define DIST_THR 900.0f

typedef unsigned short u16;
typedef _Float16 half8 __attribute__((ext_vector_type(8)));
typedef float    f32x4 __attribute__((ext_vector_type(4)));

// ---------------- kernel 1: merged prep -------------------------------------
// blocks [0,2048): convert+swizzle x -> xh/xl
// blocks [2048,6144): convert+swizzle codes -> ch/cl
// blocks [6144,10240): c2[c] = ||codes[c]||^2 (one wave per code)
//
// Swizzle: linear index c (8 halfs each):
//   r=c&15, q=(c>>4)&3, g=(c>>6)&7, kit=(c>>9)&15, tile=c>>13
//   row = tile*128 + g*16 + r ; k = kit*32 + q*8
// Each (tile,kit) is a contiguous 8KB block in exactly the fragment
// layout the GEMM wants (lane L <-> row base+(L&15), k-quad L>>4).
__device__ __forceinline__ void conv_body(const float* __restrict__ src,
                                          u16* __restrict__ dh,
                                          u16* __restrict__ dl, int c) {
    int r = c & 15, q = (c >> 4) & 3, g = (c >> 6) & 7, kit = (c >> 9) & 15;
    int tile = c >> 13;
    int row = tile * 128 + g * 16 + r;
    int k = kit * 32 + q * 8;
    const float* p = src + (size_t)row * DDIM + k;
    float4 v0 = *(const float4*)p;
    float4 v1 = *(const float4*)(p + 4);
    float vv[8] = {v0.x, v0.y, v0.z, v0.w, v1.x, v1.y, v1.z, v1.w};
    u16 hs[8], ls[8];
    #pragma unroll
    for (int j = 0; j < 8; ++j) {
        float sv = vv[j] * 16.0f;              // scale 16: keeps lo out of denorms
        _Float16 h = (_Float16)sv;
        float hf = (float)h;
        _Float16 l = (_Float16)(sv - hf);
        union { _Float16 f; u16 u; } uh, ul;
        uh.f = h; ul.f = l;
        hs[j] = uh.u; ls[j] = ul.u;
    }
    uint4 H, L;
    H.x = hs[0] | ((unsigned)hs[1] << 16); H.y = hs[2] | ((unsigned)hs[3] << 16);
    H.z = hs[4] | ((unsigned)hs[5] << 16); H.w = hs[6] | ((unsigned)hs[7] << 16);
    L.x = ls[0] | ((unsigned)ls[1] << 16); L.y = ls[2] | ((unsigned)ls[3] << 16);
    L.z = ls[4] | ((unsigned)ls[5] << 16); L.w = ls[6] | ((unsigned)ls[7] << 16);
    *(uint4*)(dh + (size_t)c * 8) = H;
    *(uint4*)(dl + (size_t)c * 8) = L;
}

__global__ __launch_bounds__(256) void nn_prep(const float* __restrict__ x,
                                               const float* __restrict__ codes,
                                               u16* __restrict__ xh, u16* __restrict__ xl,
                                               u16* __restrict__ ch, u16* __restrict__ cl,
                                               float* __restrict__ c2) {
    int b = blockIdx.x;
    if (b < 2048) {
        conv_body(x, xh, xl, b * 256 + threadIdx.x);
    } else if (b < 6144) {
        conv_body(codes, ch, cl, (b - 2048) * 256 + threadIdx.x);
    } else {
        int w = threadIdx.x >> 6;
        int lane = threadIdx.x & 63;
        int c = (b - 6144) * 4 + w;
        const float* p = codes + (size_t)c * DDIM + lane * 8;
        float4 v0 = *(const float4*)p;
        float4 v1 = *(const float4*)(p + 4);
        float s = v0.x*v0.x + v0.y*v0.y + v0.z*v0.z + v0.w*v0.w
                + v1.x*v1.x + v1.y*v1.y + v1.z*v1.z + v1.w*v1.w;
        #pragma unroll
        for (int off = 32; off > 0; off >>= 1) s += __shfl_down(s, off);
        if (lane == 0) c2[c] = s;
    }
}

// ---------------- kernel 2: A-direct fp16x3 MFMA GEMM + fused argmin --------
// grid = 32 mtiles * 8 chunks, blockIdx.x = mtile*8 + chunk (chunk<->XCD:
// each XCD's 32 co-resident blocks share one 4MB B-set = its L2).
// Block: 512 threads = 8 waves (wm=wave&3 row-quarter, wn=wave>>2 col-half);
// block tile 256 rows x 256 cols per nt (nt=0..7 over CHUNK=2048).
// Wave tile 64x128. A: global->VGPR, prefetched one iteration ahead.
// LDS: 2 x 32KB B-only ping-pong [Bh 16K|Bl 16K] + 4KB argmin table.
__global__ __launch_bounds__(512, 2) void nn_gemm(const u16* __restrict__ xh,
                                                  const u16* __restrict__ xl,
                                                  const u16* __restrict__ chh,
                                                  const u16* __restrict__ cll,
                                                  const float* __restrict__ c2,
                                                  float* __restrict__ pmin,
                                                  int* __restrict__ pid) {
    __shared__ __align__(16) char smem[69632];
    const int tid = threadIdx.x;
    const int lane = tid & 63;
    const int wave = tid >> 6;          // 0..7
    const int wm = wave & 3;            // 64-row quarter
    const int wn = wave >> 2;           // 128-col half
    const int mtile = blockIdx.x >> 3;  // 0..31
    const int chunk = blockIdx.x & 7;   // 0..7
    const int m0 = mtile * 256;
    char* tb = smem + 65536;            // 512 x int2 running (val,id) table

    // init running-min table; entry tid is owned (written+read) by wave
    // tid>>6 = the (wm,wn) wave that updates it. it=0 barrier orders it.
    if (tid < 512) {
        int2 e; e.x = __float_as_int(3.4e38f); e.y = 0;
        *(int2*)(tb + tid * 8) = e;
    }

    // A fragment global bases (R8-verified addressing):
    // frag(i,kit) at abase + kit*4096 + i*512 (halves).
    const u16* abase_h = xh + (size_t)(mtile * 2 + (wm >> 1)) * 65536
                            + (size_t)((wm & 1) * 4) * 512 + lane * 8;
    const u16* abase_l = xl + (size_t)(mtile * 2 + (wm >> 1)) * 65536
                            + (size_t)((wm & 1) * 4) * 512 + lane * 8;

    // B staging role (R8-verified): q = wave>>2 plane (Bh/Bl), s = wave&3
    // -> (s>>1) = which of the nt-pair's 2 tiles, (s&1) = which 4KB half.
    const int q = wave >> 2;
    const int s = wave & 3;
    const u16* bsrc = q ? cll : chh;
    const u16* bgbase = bsrc + (size_t)(chunk * 16 + (s >> 1)) * 65536
                             + (size_t)(s & 1) * 2048 + lane * 8;
    const int bldsoff = q * 16384 + (s >> 1) * 8192 + (s & 1) * 4096 + lane * 16;

    f32x4 acc[4][8];
    #pragma unroll
    for (int i = 0; i < 4; ++i)
        #pragma unroll
        for (int j = 0; j < 8; ++j) acc[i][j] = (f32x4)0.0f;

    // stage B for iteration it2 = nt*16 + kit into buffer (it2&1)
    auto stageB = [&](int it2) {
        int kit2 = it2 & 15, nt2 = it2 >> 4;
        const u16* src = bgbase + (size_t)nt2 * 131072 + (size_t)kit2 * 4096;
        char* dst = smem + (it2 & 1) * 32768 + bldsoff;
        #pragma unroll
        for (int jj = 0; jj < 4; ++jj)
            __builtin_amdgcn_global_load_lds(
                (const __attribute__((address_space(1))) void*)(src + jj * 512),
                (__attribute__((address_space(3))) void*)(dst + jj * 1024),
                16, 0, 0);
    };
    auto loadA = [&](int it2, half8 (&h)[4], half8 (&l)[4]) {
        int kit2 = it2 & 15;
        #pragma unroll
        for (int i = 0; i < 4; ++i) {
            h[i] = *(const half8*)(abase_h + (size_t)kit2 * 4096 + i * 512);
            l[i] = *(const half8*)(abase_l + (size_t)kit2 * 4096 + i * 512);
        }
    };

    // per-nt argmin epilogue: local min -> shfl-reduce -> owner-lane table RMW
    auto epilogue = [&](int it, f32x4 (&a)[4][8]) {
        int nt = it >> 4;
        float mvs[16]; int mis[16];
        #pragma unroll
        for (int t = 0; t < 16; ++t) { mvs[t] = 3.4e38f; mis[t] = 0; }
        #pragma unroll
        for (int j = 0; j < 8; ++j) {
            int ncol = nt * 256 + wn * 128 + j * 16 + (lane & 15);
            int gid = chunk * CHUNK + ncol;
            float cv = c2[gid];
            #pragma unroll
            for (int i = 0; i < 4; ++i)
                #pragma unroll
                for (int r = 0; r < 4; ++r) {
                    float sc = fmaf(a[i][j][r], -0.0078125f, cv);
                    int slot = i * 4 + r;
                    if (sc < mvs[slot]) { mvs[slot] = sc; mis[slot] = gid; }
                }
        }
        #pragma unroll
        for (int off = 1; off < 16; off <<= 1) {
            #pragma unroll
            for (int t = 0; t < 16; ++t) {
                float ov = __shfl_xor(mvs[t], off);
                int   oi = __shfl_xor(mis[t], off);
                if (ov < mvs[t] || (ov == mvs[t] && oi < mis[t])) { mvs[t] = ov; mis[t] = oi; }
            }
        }
        if ((lane & 15) == 0) {
            #pragma unroll
            for (int t = 0; t < 16; ++t) {
                int row = wm * 64 + (t >> 2) * 16 + (lane >> 4) * 4 + (t & 3);
                int2* e = (int2*)(tb + (wn * 256 + row) * 8);
                if (mvs[t] < __int_as_float(e->x)) {   // nt ascends: '<' keeps first
                    int2 w2; w2.x = __float_as_int(mvs[t]); w2.y = mis[t];
                    *e = w2;
                }
            }
        }
        #pragma unroll
        for (int i = 0; i < 4; ++i)
            #pragma unroll
            for (int j = 0; j < 8; ++j) a[i][j] = (f32x4)0.0f;
    };

    // iteration body: consumes A(it) from (ch,cl) regs, prefetches A(it+1)
    // into (nh,nl). Single barrier; stage(it)/A(it) are one iteration old
    // at the vmcnt(0) -> free drain.
    auto body = [&](int it, half8 (&cah)[4], half8 (&cal)[4],
                    half8 (&nah)[4], half8 (&nal)[4]) {
        asm volatile("s_waitcnt vmcnt(0)\n\ts_barrier" ::: "memory");
        const char* cur = smem + (it & 1) * 32768;
        if (it < 127) { stageB(it + 1); loadA(it + 1, nah, nal); }

        half8 bbh[2], bbl[2];
        bbh[0] = *(const half8*)(cur +         (wn * 8 + 0) * 1024 + lane * 16);
        bbl[0] = *(const half8*)(cur + 16384 + (wn * 8 + 0) * 1024 + lane * 16);
        bbh[1] = *(const half8*)(cur +         (wn * 8 + 1) * 1024 + lane * 16);
        bbl[1] = *(const half8*)(cur + 16384 + (wn * 8 + 1) * 1024 + lane * 16);

        #pragma unroll
        for (int j = 0; j < 8; ++j) {           // full unroll: j&1 static
            half8 bh = bbh[j & 1], bl = bbl[j & 1];
            #pragma unroll
            for (int i = 0; i < 4; ++i) {
                acc[i][j] = __builtin_amdgcn_mfma_f32_16x16x32_f16(cah[i], bh, acc[i][j], 0, 0, 0);
                acc[i][j] = __builtin_amdgcn_mfma_f32_16x16x32_f16(cah[i], bl, acc[i][j], 0, 0, 0);
                acc[i][j] = __builtin_amdgcn_mfma_f32_16x16x32_f16(cal[i], bh, acc[i][j], 0, 0, 0);
            }
            if (j < 6) {
                // depth-2 prefetch: B(j+2) refills the slot just consumed.
                int g = wn * 8 + j + 2;
                bbh[j & 1] = *(const half8*)(cur +         g * 1024 + lane * 16);
                bbl[j & 1] = *(const half8*)(cur + 16384 + g * 1024 + lane * 16);
                __builtin_amdgcn_sched_barrier(0);
            }
        }
        if ((it & 15) == 15) epilogue(it, acc);
    };

    half8 aXh[4], aXl[4], aYh[4], aYl[4];
    stageB(0);
    loadA(0, aXh, aXl);
    for (int it2 = 0; it2 < 64; ++it2) {        // 2x unroll: static A dbuf
        body(2 * it2,     aXh, aXl, aYh, aYl);
        body(2 * it2 + 1, aYh, aYl, aXh, aXl);
    }

    __syncthreads();
    if (tid < 256) {
        int2 e0 = *(const int2*)(tb + tid * 8);
        int2 e1 = *(const int2*)(tb + (256 + tid) * 8);
        float v0 = __int_as_float(e0.x), v1 = __int_as_float(e1.x);
        float bv = v0; int bi = e0.y;
        if (v1 < bv || (v1 == bv && e1.y < bi)) { bv = v1; bi = e1.y; }
        pmin[(size_t)(m0 + tid) * NCHUNK + chunk] = bv;
        pid [(size_t)(m0 + tid) * NCHUNK + chunk] = bi;
    }
}

// ---------------- kernel 3: finalize (one wave per token) -------------------
__global__ __launch_bounds__(256) void nn_fin(const float* __restrict__ x,
                                              const float* __restrict__ pmin,
                                              const int* __restrict__ pid,
                                              int* __restrict__ out) {
    int w = threadIdx.x >> 6;
    int lane = threadIdx.x & 63;
    int t = blockIdx.x * 4 + w;
    const float* p = x + (size_t)t * DDIM + lane * 8;
    float4 v0 = *(const float4*)p;
    float4 v1 = *(const float4*)(p + 4);
    float s = v0.x*v0.x + v0.y*v0.y + v0.z*v0.z + v0.w*v0.w
            + v1.x*v1.x + v1.y*v1.y + v1.z*v1.z + v1.w*v1.w;
    #pragma unroll
    for (int off = 32; off > 0; off >>= 1) s += __shfl_down(s, off);
    if (lane == 0) {
        const float* pm = pmin + (size_t)t * NCHUNK;
        const int*   pi = pid  + (size_t)t * NCHUNK;
        float bv = pm[0]; int bi = pi[0];
        #pragma unroll
        for (int c = 1; c < NCHUNK; ++c) {
            float v = pm[c]; int id = pi[c];
            if (v < bv || (v == bv && id < bi)) { bv = v; bi = id; }
        }
        float mind = s + bv;   // ||x||^2 + min(||c||^2 - 2 x.c)
        out[t] = (mind <= DIST_THR) ? bi : -1;
    }
}

extern "C" void kernel_launch(void* const* d_in, const int* in_sizes, int n_in,
                              void* d_out, int out_size, void* d_ws, size_t ws_size,
                              hipStream_t stream) {
    const float* x     = (const float*)d_in[0];
    const float* codes = (const float*)d_in[1];
    int* out = (int*)d_out;

    // workspace layout (bytes):
    //  xh 8MB | xl 8MB | ch 16MB | cl 16MB | c2 64KB | pmin 256KB | pid 256KB
    char* ws = (char*)d_ws;
    u16*   xh   = (u16*)(ws);
    u16*   xl   = (u16*)(ws + 8388608);
    u16*   chh  = (u16*)(ws + 16777216);
    u16*   cll  = (u16*)(ws + 33554432);
    float* c2   = (float*)(ws + 50331648);
    float* pmin = (float*)(ws + 50397184);
    int*   pid  = (int*)  (ws + 50659328);

    nn_prep<<<10240, 256, 0, stream>>>(x, codes, xh, xl, chh, cll, c2);
    nn_gemm<<<32 * NCHUNK, 512, 0, stream>>>(xh, xl, chh, cll, c2, pmin, pid);
    nn_fin<<<NTOK / 4, 256, 0, stream>>>(x, pmin, pid, out);
}

// Round 9
// 397.616 us; speedup vs baseline: 1.1563x; 1.1563x over previous
//
#include <hip/hip_runtime.h>

// NearestNeighborTokenizer: ids = (min_c ||x - c||^2 <= 900) ? argmin_c : -1
// x: [8192, 512] fp32, codes: [16384, 512] fp32, out: [8192] int32
//
// fp16x3 MFMA GEMM: x,c scaled by 16, split into fp16 hi+lo planes,
// pre-swizzled in global memory into MFMA fragment order. dot =
// (hh + hl + lh)/256 in one fp32 acc. score = ||c||^2 - 2*dot.
//
// R14 = R12 (champion, 298us gemm) + peeled-j0 head reduction.
// R13 post-mortem: A-direct = R8 = 371us regardless of prefetch depth
// -> A-vmem is a THROUGHPUT wall (A slabs miss the XCD L2 - 16MB of
// A-slabs vs 4MB L2/XCD - and L3-served reads cost ~2400cyc/iter);
// A stays on the LDS path. Closed.
// R12 budget: 5600 cyc/iter vs 3954 MFMA floor; reads/wave-iter (24)
// is geometry-invariant. Remaining serial piece: the iteration head
// (12 ds_reads before the first MFMA). This round: peel j=0 and
// interleave the A[1..3] reads between its 3-MFMA sub-clusters so the
// first MFMA waits on only 6 reads; each A-read pair gets ~120cyc of
// MFMA cover. sched_barrier(0) pins each step. Rest identical to R12.

#define NTOK   8192
#define NCODES 16384
#define DDIM   512
#define NCHUNK 8
#define CHUNK  2048
#define DIST_THR 900.0f

typedef unsigned short u16;
typedef _Float16 half8 __attribute__((ext_vector_type(8)));
typedef float    f32x4 __attribute__((ext_vector_type(4)));

// ---------------- kernel 1: merged prep -------------------------------------
// blocks [0,2048): convert+swizzle x -> xh/xl
// blocks [2048,6144): convert+swizzle codes -> ch/cl
// blocks [6144,10240): c2[c] = ||codes[c]||^2 (one wave per code)
//
// Swizzle: linear index c (8 halfs each):
//   r=c&15, q=(c>>4)&3, g=(c>>6)&7, kit=(c>>9)&15, tile=c>>13
//   row = tile*128 + g*16 + r ; k = kit*32 + q*8
// Each (tile,kit) is a contiguous 8KB block in exactly the LDS fragment
// layout the GEMM wants (lane L <-> row base+(L&15), k-quad L>>4).
__device__ __forceinline__ void conv_body(const float* __restrict__ src,
                                          u16* __restrict__ dh,
                                          u16* __restrict__ dl, int c) {
    int r = c & 15, q = (c >> 4) & 3, g = (c >> 6) & 7, kit = (c >> 9) & 15;
    int tile = c >> 13;
    int row = tile * 128 + g * 16 + r;
    int k = kit * 32 + q * 8;
    const float* p = src + (size_t)row * DDIM + k;
    float4 v0 = *(const float4*)p;
    float4 v1 = *(const float4*)(p + 4);
    float vv[8] = {v0.x, v0.y, v0.z, v0.w, v1.x, v1.y, v1.z, v1.w};
    u16 hs[8], ls[8];
    #pragma unroll
    for (int j = 0; j < 8; ++j) {
        float sv = vv[j] * 16.0f;              // scale 16: keeps lo out of denorms
        _Float16 h = (_Float16)sv;
        float hf = (float)h;
        _Float16 l = (_Float16)(sv - hf);
        union { _Float16 f; u16 u; } uh, ul;
        uh.f = h; ul.f = l;
        hs[j] = uh.u; ls[j] = ul.u;
    }
    uint4 H, L;
    H.x = hs[0] | ((unsigned)hs[1] << 16); H.y = hs[2] | ((unsigned)hs[3] << 16);
    H.z = hs[4] | ((unsigned)hs[5] << 16); H.w = hs[6] | ((unsigned)hs[7] << 16);
    L.x = ls[0] | ((unsigned)ls[1] << 16); L.y = ls[2] | ((unsigned)ls[3] << 16);
    L.z = ls[4] | ((unsigned)ls[5] << 16); L.w = ls[6] | ((unsigned)ls[7] << 16);
    *(uint4*)(dh + (size_t)c * 8) = H;
    *(uint4*)(dl + (size_t)c * 8) = L;
}

__global__ __launch_bounds__(256) void nn_prep(const float* __restrict__ x,
                                               const float* __restrict__ codes,
                                               u16* __restrict__ xh, u16* __restrict__ xl,
                                               u16* __restrict__ ch, u16* __restrict__ cl,
                                               float* __restrict__ c2) {
    int b = blockIdx.x;
    if (b < 2048) {
        conv_body(x, xh, xl, b * 256 + threadIdx.x);
    } else if (b < 6144) {
        conv_body(codes, ch, cl, (b - 2048) * 256 + threadIdx.x);
    } else {
        int w = threadIdx.x >> 6;
        int lane = threadIdx.x & 63;
        int c = (b - 6144) * 4 + w;
        const float* p = codes + (size_t)c * DDIM + lane * 8;
        float4 v0 = *(const float4*)p;
        float4 v1 = *(const float4*)(p + 4);
        float s = v0.x*v0.x + v0.y*v0.y + v0.z*v0.z + v0.w*v0.w
                + v1.x*v1.x + v1.y*v1.y + v1.z*v1.z + v1.w*v1.w;
        #pragma unroll
        for (int off = 32; off > 0; off >>= 1) s += __shfl_down(s, off);
        if (lane == 0) c2[c] = s;
    }
}

// ---------------- kernel 2: pipelined fp16x3 MFMA GEMM + fused argmin -------
// grid = 32 mtiles * 8 chunks, blockIdx.x = mtile*8 + chunk (chunk<->XCD:
// each XCD's 32 co-resident blocks share one 4MB B-set = its L2).
// Block: 512 threads = 8 waves (wm=wave&3 row-quarter, wn=wave>>2 col-half);
// block tile 256 rows x 256 cols per nt (nt=0..7 over CHUNK=2048).
// Wave tile 64x128. LDS: 2 x 64KB ping-pong [Ah 16K|Al 16K|Bh 16K|Bl 16K].
__global__ __launch_bounds__(512, 2) void nn_gemm(const u16* __restrict__ xh,
                                                  const u16* __restrict__ xl,
                                                  const u16* __restrict__ chh,
                                                  const u16* __restrict__ cll,
                                                  const float* __restrict__ c2,
                                                  float* __restrict__ pmin,
                                                  int* __restrict__ pid) {
    __shared__ __align__(16) char smem[131072];
    const int tid = threadIdx.x;
    const int lane = tid & 63;
    const int wave = tid >> 6;          // 0..7
    const int wm = wave & 3;            // 64-row quarter
    const int wn = wave >> 2;           // 128-col half
    const int mtile = blockIdx.x >> 3;  // 0..31
    const int chunk = blockIdx.x & 7;   // 0..7
    const int m0 = mtile * 256;

    // wave-static staging role: plane = wave>>1 (0 Ah,1 Al,2 Bh,3 Bl),
    // tsub = wave&1 selects which 128-row/col subtile of the 256-tile.
    const int plane = wave >> 1;
    const int tsub  = wave & 1;
    const bool isA = (plane < 2);
    const u16* gbase;
    if (plane == 0)      gbase = xh  + ((size_t)(mtile * 2 + tsub) * 16) * 4096;
    else if (plane == 1) gbase = xl  + ((size_t)(mtile * 2 + tsub) * 16) * 4096;
    else if (plane == 2) gbase = chh + ((size_t)(chunk * 16 + tsub) * 16) * 4096;
    else                 gbase = cll + ((size_t)(chunk * 16 + tsub) * 16) * 4096;
    gbase += lane * 8;
    // LDS dst region for this wave: plane p at p*16KB, subtile at tsub*8KB
    const int ldsoff = wave * 8192;     // == plane*16384 + tsub*8192

    float mv[16];
    int   mi[16];
    #pragma unroll
    for (int s = 0; s < 16; ++s) { mv[s] = 3.4e38f; mi[s] = 0; }

    f32x4 acc[4][8];
    #pragma unroll
    for (int i = 0; i < 4; ++i)
        #pragma unroll
        for (int j = 0; j < 8; ++j) acc[i][j] = (f32x4)0.0f;

    // stage iteration it2 = nt*16 + kit into buffer (it2&1)
    auto stage = [&](int it2) {
        int kit2 = it2 & 15, nt2 = it2 >> 4;
        size_t off = (size_t)(isA ? kit2 : nt2 * 32 + kit2) * 4096;
        const u16* src = gbase + off;
        char* dst = smem + (size_t)(it2 & 1) * 65536 + ldsoff;
        #pragma unroll
        for (int s = 0; s < 8; ++s)
            __builtin_amdgcn_global_load_lds(
                (const __attribute__((address_space(1))) void*)(src + s * 512),
                (__attribute__((address_space(3))) void*)(dst + s * 1024),
                16, 0, 0);
    };

    stage(0);
    for (int it = 0; it < 128; ++it) {
        // single barrier per iteration: stage(it) was issued a full body
        // ago -> vmcnt(0) is ~free. All waves' reads of buf[(it+1)&1]
        // finished in body(it-1) (their last MFMA lgkm wait covers them),
        // so stage(it+1) issued below cannot race.
        asm volatile("s_waitcnt vmcnt(0)\n\ts_barrier" ::: "memory");
        const char* cur = smem + (size_t)(it & 1) * 65536;
        if (it < 127) stage(it + 1);

        // minimal head: B(0),B(1) + A(0) only (6 reads) before first MFMA.
        half8 bbh[2], bbl[2];
        bbh[0] = *(const half8*)(cur + 32768 + (wn * 8 + 0) * 1024 + lane * 16);
        bbl[0] = *(const half8*)(cur + 49152 + (wn * 8 + 0) * 1024 + lane * 16);
        bbh[1] = *(const half8*)(cur + 32768 + (wn * 8 + 1) * 1024 + lane * 16);
        bbl[1] = *(const half8*)(cur + 49152 + (wn * 8 + 1) * 1024 + lane * 16);
        half8 ah[4], al[4];
        ah[0] = *(const half8*)(cur +         (wm * 4) * 1024 + lane * 16);
        al[0] = *(const half8*)(cur + 16384 + (wm * 4) * 1024 + lane * 16);

        // peeled j=0 cluster: A[i+1] reads interleave with the 3-MFMA
        // sub-clusters (~120cyc cover each); SB(0) pins each step.
        #pragma unroll
        for (int i = 0; i < 4; ++i) {
            if (i < 3) {
                int g = wm * 4 + i + 1;
                ah[i + 1] = *(const half8*)(cur +         g * 1024 + lane * 16);
                al[i + 1] = *(const half8*)(cur + 16384 + g * 1024 + lane * 16);
            }
            acc[i][0] = __builtin_amdgcn_mfma_f32_16x16x32_f16(ah[i], bbh[0], acc[i][0], 0, 0, 0);
            acc[i][0] = __builtin_amdgcn_mfma_f32_16x16x32_f16(ah[i], bbl[0], acc[i][0], 0, 0, 0);
            acc[i][0] = __builtin_amdgcn_mfma_f32_16x16x32_f16(al[i], bbh[0], acc[i][0], 0, 0, 0);
            __builtin_amdgcn_sched_barrier(0);
        }
        // refill slot 0 with B(2) (the rotation step j=0 would have done)
        {
            int g = wn * 8 + 2;
            bbh[0] = *(const half8*)(cur + 32768 + g * 1024 + lane * 16);
            bbl[0] = *(const half8*)(cur + 49152 + g * 1024 + lane * 16);
            __builtin_amdgcn_sched_barrier(0);
        }

        #pragma unroll
        for (int j = 1; j < 8; ++j) {           // full unroll: j&1 static
            half8 bh = bbh[j & 1], bl = bbl[j & 1];
            #pragma unroll
            for (int i = 0; i < 4; ++i) {
                acc[i][j] = __builtin_amdgcn_mfma_f32_16x16x32_f16(ah[i], bh, acc[i][j], 0, 0, 0);
                acc[i][j] = __builtin_amdgcn_mfma_f32_16x16x32_f16(ah[i], bl, acc[i][j], 0, 0, 0);
                acc[i][j] = __builtin_amdgcn_mfma_f32_16x16x32_f16(al[i], bh, acc[i][j], 0, 0, 0);
            }
            if (j < 6) {
                // depth-2 prefetch: B(j+2) refills the slot just consumed.
                int g = wn * 8 + j + 2;
                bbh[j & 1] = *(const half8*)(cur + 32768 + g * 1024 + lane * 16);
                bbl[j & 1] = *(const half8*)(cur + 49152 + g * 1024 + lane * 16);
                // pin: next j's MFMAs may not hoist above these reads.
                __builtin_amdgcn_sched_barrier(0);
            }
        }

        if ((it & 15) == 15) {
            // epilogue for nt: score = ||c||^2 - acc/128 (acc = 256 * x.c).
            // candidates arrive in increasing code id -> '<' keeps first.
            int nt = it >> 4;
            #pragma unroll
            for (int j = 0; j < 8; ++j) {
                int ncol = nt * 256 + wn * 128 + j * 16 + (lane & 15);
                int gid = chunk * CHUNK + ncol;
                float cv = c2[gid];
                #pragma unroll
                for (int i = 0; i < 4; ++i)
                    #pragma unroll
                    for (int r = 0; r < 4; ++r) {
                        float s = fmaf(acc[i][j][r], -0.0078125f, cv);
                        int slot = i * 4 + r;
                        if (s < mv[slot]) { mv[slot] = s; mi[slot] = gid; }
                    }
            }
            #pragma unroll
            for (int i = 0; i < 4; ++i)
                #pragma unroll
                for (int j = 0; j < 8; ++j) acc[i][j] = (f32x4)0.0f;
        }
    }

    // shuffle pre-reduce across the 16 col-owner lanes (xor 1,2,4,8 stay
    // within the quad; lane>>4 = row quad is preserved).
    #pragma unroll
    for (int off = 1; off < 16; off <<= 1) {
        #pragma unroll
        for (int s = 0; s < 16; ++s) {
            float ov = __shfl_xor(mv[s], off);
            int   oi = __shfl_xor(mi[s], off);
            if (ov < mv[s] || (ov == mv[s] && oi < mi[s])) { mv[s] = ov; mi[s] = oi; }
        }
    }
    // 2 contributors per row (wn=0,1); 4KB scratch aliases buf0 (all tile
    // reads finished inside the loop; it=127 read buf1 anyway).
    if ((lane & 15) == 0) {
        #pragma unroll
        for (int i = 0; i < 4; ++i)
            #pragma unroll
            for (int r = 0; r < 4; ++r) {
                int row = wm * 64 + i * 16 + (lane >> 4) * 4 + r;
                int2 e;
                e.x = __float_as_int(mv[i * 4 + r]);
                e.y = mi[i * 4 + r];
                *(int2*)(smem + (wn * 256 + row) * 8) = e;
            }
    }
    __syncthreads();
    if (tid < 256) {
        int2 e0 = *(const int2*)(smem + tid * 8);
        int2 e1 = *(const int2*)(smem + (256 + tid) * 8);
        float v0 = __int_as_float(e0.x), v1 = __int_as_float(e1.x);
        float bv = v0; int bi = e0.y;
        if (v1 < bv || (v1 == bv && e1.y < bi)) { bv = v1; bi = e1.y; }
        pmin[(size_t)(m0 + tid) * NCHUNK + chunk] = bv;
        pid [(size_t)(m0 + tid) * NCHUNK + chunk] = bi;
    }
}

// ---------------- kernel 3: finalize (one wave per token) -------------------
__global__ __launch_bounds__(256) void nn_fin(const float* __restrict__ x,
                                              const float* __restrict__ pmin,
                                              const int* __restrict__ pid,
                                              int* __restrict__ out) {
    int w = threadIdx.x >> 6;
    int lane = threadIdx.x & 63;
    int t = blockIdx.x * 4 + w;
    const float* p = x + (size_t)t * DDIM + lane * 8;
    float4 v0 = *(const float4*)p;
    float4 v1 = *(const float4*)(p + 4);
    float s = v0.x*v0.x + v0.y*v0.y + v0.z*v0.z + v0.w*v0.w
            + v1.x*v1.x + v1.y*v1.y + v1.z*v1.z + v1.w*v1.w;
    #pragma unroll
    for (int off = 32; off > 0; off >>= 1) s += __shfl_down(s, off);
    if (lane == 0) {
        const float* pm = pmin + (size_t)t * NCHUNK;
        const int*   pi = pid  + (size_t)t * NCHUNK;
        float bv = pm[0]; int bi = pi[0];
        #pragma unroll
        for (int c = 1; c < NCHUNK; ++c) {
            float v = pm[c]; int id = pi[c];
            if (v < bv || (v == bv && id < bi)) { bv = v; bi = id; }
        }
        float mind = s + bv;   // ||x||^2 + min(||c||^2 - 2 x.c)
        out[t] = (mind <= DIST_THR) ? bi : -1;
    }
}

extern "C" void kernel_launch(void* const* d_in, const int* in_sizes, int n_in,
                              void* d_out, int out_size, void* d_ws, size_t ws_size,
                              hipStream_t stream) {
    const float* x     = (const float*)d_in[0];
    const float* codes = (const float*)d_in[1];
    int* out = (int*)d_out;

    // workspace layout (bytes):
    //  xh 8MB | xl 8MB | ch 16MB | cl 16MB | c2 64KB | pmin 256KB | pid 256KB
    char* ws = (char*)d_ws;
    u16*   xh   = (u16*)(ws);
    u16*   xl   = (u16*)(ws + 8388608);
    u16*   chh  = (u16*)(ws + 16777216);
    u16*   cll  = (u16*)(ws + 33554432);
    float* c2   = (float*)(ws + 50331648);
    float* pmin = (float*)(ws + 50397184);
    int*   pid  = (int*)  (ws + 50659328);

    nn_prep<<<10240, 256, 0, stream>>>(x, codes, xh, xl, chh, cll, c2);
    nn_gemm<<<32 * NCHUNK, 512, 0, stream>>>(xh, xl, chh, cll, c2, pmin, pid);
    nn_fin<<<NTOK / 4, 256, 0, stream>>>(x, pmin, pid, out);
}

// Round 10
// 389.457 us; speedup vs baseline: 1.1805x; 1.0209x over previous
//
#include <hip/hip_runtime.h>

// NearestNeighborTokenizer: ids = (min_c ||x - c||^2 <= 900) ? argmin_c : -1
// x: [8192, 512] fp32, codes: [16384, 512] fp32, out: [8192] int32
//
// fp16x3 MFMA GEMM: x,c scaled by 16, split into fp16 hi+lo planes,
// pre-swizzled in global memory into MFMA fragment order. dot =
// (hh + hl + lh)/256 in one fp32 acc. score = ||c||^2 - 2*dot.
//
// R15 == R12 (champion, 298us gemm / 386.8us total) reverted after the
// R14 head-pin regression (331us, MfmaUtil 58: pinned read/MFMA
// interleave blocks the compiler's overlapped 12-read head; third
// failed hand-schedule -> K-loop closed). R12 structure:
// (1) depth-2 B-fragment prefetch: explicit 2-slot rotation, B(j+2)
//     issued right after MFMA cluster j (+sched_barrier pin) -> ~116cyc
//     runway vs ~120cyc loaded ds_read latency.
// (2) single barrier per iteration: vmcnt(0)+s_barrier at body TOP
//     (drains stage(it) issued a full iteration ago -> free wait);
//     stage(it+1) issued after the barrier.
// Ledger: gemm = 71% of the 1955TF f16-16x16 ceiling (plain-HIP SOTA
// territory; m201 template = 62%, MfmaUtil 64 vs 62.1, zero bank
// conflicts); A-direct refuted 2x (L2-capacity wall); 32x32 refuted
// (dep-chain + compiler order normalization); 4-phase/setprio null.

#define NTOK   8192
#define NCODES 16384
#define DDIM   512
#define NCHUNK 8
#define CHUNK  2048
#define DIST_THR 900.0f

typedef unsigned short u16;
typedef _Float16 half8 __attribute__((ext_vector_type(8)));
typedef float    f32x4 __attribute__((ext_vector_type(4)));

// ---------------- kernel 1: merged prep -------------------------------------
// blocks [0,2048): convert+swizzle x -> xh/xl
// blocks [2048,6144): convert+swizzle codes -> ch/cl
// blocks [6144,10240): c2[c] = ||codes[c]||^2 (one wave per code)
//
// Swizzle: linear index c (8 halfs each):
//   r=c&15, q=(c>>4)&3, g=(c>>6)&7, kit=(c>>9)&15, tile=c>>13
//   row = tile*128 + g*16 + r ; k = kit*32 + q*8
// Each (tile,kit) is a contiguous 8KB block in exactly the LDS fragment
// layout the GEMM wants (lane L <-> row base+(L&15), k-quad L>>4).
__device__ __forceinline__ void conv_body(const float* __restrict__ src,
                                          u16* __restrict__ dh,
                                          u16* __restrict__ dl, int c) {
    int r = c & 15, q = (c >> 4) & 3, g = (c >> 6) & 7, kit = (c >> 9) & 15;
    int tile = c >> 13;
    int row = tile * 128 + g * 16 + r;
    int k = kit * 32 + q * 8;
    const float* p = src + (size_t)row * DDIM + k;
    float4 v0 = *(const float4*)p;
    float4 v1 = *(const float4*)(p + 4);
    float vv[8] = {v0.x, v0.y, v0.z, v0.w, v1.x, v1.y, v1.z, v1.w};
    u16 hs[8], ls[8];
    #pragma unroll
    for (int j = 0; j < 8; ++j) {
        float sv = vv[j] * 16.0f;              // scale 16: keeps lo out of denorms
        _Float16 h = (_Float16)sv;
        float hf = (float)h;
        _Float16 l = (_Float16)(sv - hf);
        union { _Float16 f; u16 u; } uh, ul;
        uh.f = h; ul.f = l;
        hs[j] = uh.u; ls[j] = ul.u;
    }
    uint4 H, L;
    H.x = hs[0] | ((unsigned)hs[1] << 16); H.y = hs[2] | ((unsigned)hs[3] << 16);
    H.z = hs[4] | ((unsigned)hs[5] << 16); H.w = hs[6] | ((unsigned)hs[7] << 16);
    L.x = ls[0] | ((unsigned)ls[1] << 16); L.y = ls[2] | ((unsigned)ls[3] << 16);
    L.z = ls[4] | ((unsigned)ls[5] << 16); L.w = ls[6] | ((unsigned)ls[7] << 16);
    *(uint4*)(dh + (size_t)c * 8) = H;
    *(uint4*)(dl + (size_t)c * 8) = L;
}

__global__ __launch_bounds__(256) void nn_prep(const float* __restrict__ x,
                                               const float* __restrict__ codes,
                                               u16* __restrict__ xh, u16* __restrict__ xl,
                                               u16* __restrict__ ch, u16* __restrict__ cl,
                                               float* __restrict__ c2) {
    int b = blockIdx.x;
    if (b < 2048) {
        conv_body(x, xh, xl, b * 256 + threadIdx.x);
    } else if (b < 6144) {
        conv_body(codes, ch, cl, (b - 2048) * 256 + threadIdx.x);
    } else {
        int w = threadIdx.x >> 6;
        int lane = threadIdx.x & 63;
        int c = (b - 6144) * 4 + w;
        const float* p = codes + (size_t)c * DDIM + lane * 8;
        float4 v0 = *(const float4*)p;
        float4 v1 = *(const float4*)(p + 4);
        float s = v0.x*v0.x + v0.y*v0.y + v0.z*v0.z + v0.w*v0.w
                + v1.x*v1.x + v1.y*v1.y + v1.z*v1.z + v1.w*v1.w;
        #pragma unroll
        for (int off = 32; off > 0; off >>= 1) s += __shfl_down(s, off);
        if (lane == 0) c2[c] = s;
    }
}

// ---------------- kernel 2: pipelined fp16x3 MFMA GEMM + fused argmin -------
// grid = 32 mtiles * 8 chunks, blockIdx.x = mtile*8 + chunk (chunk<->XCD:
// each XCD's 32 co-resident blocks share one 4MB B-set = its L2).
// Block: 512 threads = 8 waves (wm=wave&3 row-quarter, wn=wave>>2 col-half);
// block tile 256 rows x 256 cols per nt (nt=0..7 over CHUNK=2048).
// Wave tile 64x128. LDS: 2 x 64KB ping-pong [Ah 16K|Al 16K|Bh 16K|Bl 16K].
__global__ __launch_bounds__(512, 2) void nn_gemm(const u16* __restrict__ xh,
                                                  const u16* __restrict__ xl,
                                                  const u16* __restrict__ chh,
                                                  const u16* __restrict__ cll,
                                                  const float* __restrict__ c2,
                                                  float* __restrict__ pmin,
                                                  int* __restrict__ pid) {
    __shared__ __align__(16) char smem[131072];
    const int tid = threadIdx.x;
    const int lane = tid & 63;
    const int wave = tid >> 6;          // 0..7
    const int wm = wave & 3;            // 64-row quarter
    const int wn = wave >> 2;           // 128-col half
    const int mtile = blockIdx.x >> 3;  // 0..31
    const int chunk = blockIdx.x & 7;   // 0..7
    const int m0 = mtile * 256;

    // wave-static staging role: plane = wave>>1 (0 Ah,1 Al,2 Bh,3 Bl),
    // tsub = wave&1 selects which 128-row/col subtile of the 256-tile.
    const int plane = wave >> 1;
    const int tsub  = wave & 1;
    const bool isA = (plane < 2);
    const u16* gbase;
    if (plane == 0)      gbase = xh  + ((size_t)(mtile * 2 + tsub) * 16) * 4096;
    else if (plane == 1) gbase = xl  + ((size_t)(mtile * 2 + tsub) * 16) * 4096;
    else if (plane == 2) gbase = chh + ((size_t)(chunk * 16 + tsub) * 16) * 4096;
    else                 gbase = cll + ((size_t)(chunk * 16 + tsub) * 16) * 4096;
    gbase += lane * 8;
    // LDS dst region for this wave: plane p at p*16KB, subtile at tsub*8KB
    const int ldsoff = wave * 8192;     // == plane*16384 + tsub*8192

    float mv[16];
    int   mi[16];
    #pragma unroll
    for (int s = 0; s < 16; ++s) { mv[s] = 3.4e38f; mi[s] = 0; }

    f32x4 acc[4][8];
    #pragma unroll
    for (int i = 0; i < 4; ++i)
        #pragma unroll
        for (int j = 0; j < 8; ++j) acc[i][j] = (f32x4)0.0f;

    // stage iteration it2 = nt*16 + kit into buffer (it2&1)
    auto stage = [&](int it2) {
        int kit2 = it2 & 15, nt2 = it2 >> 4;
        size_t off = (size_t)(isA ? kit2 : nt2 * 32 + kit2) * 4096;
        const u16* src = gbase + off;
        char* dst = smem + (size_t)(it2 & 1) * 65536 + ldsoff;
        #pragma unroll
        for (int s = 0; s < 8; ++s)
            __builtin_amdgcn_global_load_lds(
                (const __attribute__((address_space(1))) void*)(src + s * 512),
                (__attribute__((address_space(3))) void*)(dst + s * 1024),
                16, 0, 0);
    };

    stage(0);
    for (int it = 0; it < 128; ++it) {
        // single barrier per iteration: stage(it) was issued a full body
        // ago -> vmcnt(0) is ~free. All waves' reads of buf[(it+1)&1]
        // finished in body(it-1) (their last MFMA lgkm wait covers them),
        // so stage(it+1) issued below cannot race.
        asm volatile("s_waitcnt vmcnt(0)\n\ts_barrier" ::: "memory");
        const char* cur = smem + (size_t)(it & 1) * 65536;
        if (it < 127) stage(it + 1);

        // prologue reads: B(0),B(1) into the 2-slot rotation + 8 A frags
        half8 bbh[2], bbl[2];
        bbh[0] = *(const half8*)(cur + 32768 + (wn * 8 + 0) * 1024 + lane * 16);
        bbl[0] = *(const half8*)(cur + 49152 + (wn * 8 + 0) * 1024 + lane * 16);
        bbh[1] = *(const half8*)(cur + 32768 + (wn * 8 + 1) * 1024 + lane * 16);
        bbl[1] = *(const half8*)(cur + 49152 + (wn * 8 + 1) * 1024 + lane * 16);
        half8 ah[4], al[4];
        #pragma unroll
        for (int i = 0; i < 4; ++i) {
            int g = wm * 4 + i;                 // A group (16 rows each)
            ah[i] = *(const half8*)(cur +         g * 1024 + lane * 16);
            al[i] = *(const half8*)(cur + 16384 + g * 1024 + lane * 16);
        }

        #pragma unroll
        for (int j = 0; j < 8; ++j) {           // full unroll: j&1 static
            half8 bh = bbh[j & 1], bl = bbl[j & 1];
            #pragma unroll
            for (int i = 0; i < 4; ++i) {
                acc[i][j] = __builtin_amdgcn_mfma_f32_16x16x32_f16(ah[i], bh, acc[i][j], 0, 0, 0);
                acc[i][j] = __builtin_amdgcn_mfma_f32_16x16x32_f16(ah[i], bl, acc[i][j], 0, 0, 0);
                acc[i][j] = __builtin_amdgcn_mfma_f32_16x16x32_f16(al[i], bh, acc[i][j], 0, 0, 0);
            }
            if (j < 6) {
                // depth-2 prefetch: B(j+2) refills the slot just consumed.
                int g = wn * 8 + j + 2;
                bbh[j & 1] = *(const half8*)(cur + 32768 + g * 1024 + lane * 16);
                bbl[j & 1] = *(const half8*)(cur + 49152 + g * 1024 + lane * 16);
                // pin: next j's MFMAs may not hoist above these reads.
                __builtin_amdgcn_sched_barrier(0);
            }
        }

        if ((it & 15) == 15) {
            // epilogue for nt: score = ||c||^2 - acc/128 (acc = 256 * x.c).
            // candidates arrive in increasing code id -> '<' keeps first.
            int nt = it >> 4;
            #pragma unroll
            for (int j = 0; j < 8; ++j) {
                int ncol = nt * 256 + wn * 128 + j * 16 + (lane & 15);
                int gid = chunk * CHUNK + ncol;
                float cv = c2[gid];
                #pragma unroll
                for (int i = 0; i < 4; ++i)
                    #pragma unroll
                    for (int r = 0; r < 4; ++r) {
                        float s = fmaf(acc[i][j][r], -0.0078125f, cv);
                        int slot = i * 4 + r;
                        if (s < mv[slot]) { mv[slot] = s; mi[slot] = gid; }
                    }
            }
            #pragma unroll
            for (int i = 0; i < 4; ++i)
                #pragma unroll
                for (int j = 0; j < 8; ++j) acc[i][j] = (f32x4)0.0f;
        }
    }

    // shuffle pre-reduce across the 16 col-owner lanes (xor 1,2,4,8 stay
    // within the quad; lane>>4 = row quad is preserved).
    #pragma unroll
    for (int off = 1; off < 16; off <<= 1) {
        #pragma unroll
        for (int s = 0; s < 16; ++s) {
            float ov = __shfl_xor(mv[s], off);
            int   oi = __shfl_xor(mi[s], off);
            if (ov < mv[s] || (ov == mv[s] && oi < mi[s])) { mv[s] = ov; mi[s] = oi; }
        }
    }
    // 2 contributors per row (wn=0,1); 4KB scratch aliases buf0 (all tile
    // reads finished inside the loop; it=127 read buf1 anyway).
    if ((lane & 15) == 0) {
        #pragma unroll
        for (int i = 0; i < 4; ++i)
            #pragma unroll
            for (int r = 0; r < 4; ++r) {
                int row = wm * 64 + i * 16 + (lane >> 4) * 4 + r;
                int2 e;
                e.x = __float_as_int(mv[i * 4 + r]);
                e.y = mi[i * 4 + r];
                *(int2*)(smem + (wn * 256 + row) * 8) = e;
            }
    }
    __syncthreads();
    if (tid < 256) {
        int2 e0 = *(const int2*)(smem + tid * 8);
        int2 e1 = *(const int2*)(smem + (256 + tid) * 8);
        float v0 = __int_as_float(e0.x), v1 = __int_as_float(e1.x);
        float bv = v0; int bi = e0.y;
        if (v1 < bv || (v1 == bv && e1.y < bi)) { bv = v1; bi = e1.y; }
        pmin[(size_t)(m0 + tid) * NCHUNK + chunk] = bv;
        pid [(size_t)(m0 + tid) * NCHUNK + chunk] = bi;
    }
}

// ---------------- kernel 3: finalize (one wave per token) -------------------
__global__ __launch_bounds__(256) void nn_fin(const float* __restrict__ x,
                                              const float* __restrict__ pmin,
                                              const int* __restrict__ pid,
                                              int* __restrict__ out) {
    int w = threadIdx.x >> 6;
    int lane = threadIdx.x & 63;
    int t = blockIdx.x * 4 + w;
    const float* p = x + (size_t)t * DDIM + lane * 8;
    float4 v0 = *(const float4*)p;
    float4 v1 = *(const float4*)(p + 4);
    float s = v0.x*v0.x + v0.y*v0.y + v0.z*v0.z + v0.w*v0.w
            + v1.x*v1.x + v1.y*v1.y + v1.z*v1.z + v1.w*v1.w;
    #pragma unroll
    for (int off = 32; off > 0; off >>= 1) s += __shfl_down(s, off);
    if (lane == 0) {
        const float* pm = pmin + (size_t)t * NCHUNK;
        const int*   pi = pid  + (size_t)t * NCHUNK;
        float bv = pm[0]; int bi = pi[0];
        #pragma unroll
        for (int c = 1; c < NCHUNK; ++c) {
            float v = pm[c]; int id = pi[c];
            if (v < bv || (v == bv && id < bi)) { bv = v; bi = id; }
        }
        float mind = s + bv;   // ||x||^2 + min(||c||^2 - 2 x.c)
        out[t] = (mind <= DIST_THR) ? bi : -1;
    }
}

extern "C" void kernel_launch(void* const* d_in, const int* in_sizes, int n_in,
                              void* d_out, int out_size, void* d_ws, size_t ws_size,
                              hipStream_t stream) {
    const float* x     = (const float*)d_in[0];
    const float* codes = (const float*)d_in[1];
    int* out = (int*)d_out;

    // workspace layout (bytes):
    //  xh 8MB | xl 8MB | ch 16MB | cl 16MB | c2 64KB | pmin 256KB | pid 256KB
    char* ws = (char*)d_ws;
    u16*   xh   = (u16*)(ws);
    u16*   xl   = (u16*)(ws + 8388608);
    u16*   chh  = (u16*)(ws + 16777216);
    u16*   cll  = (u16*)(ws + 33554432);
    float* c2   = (float*)(ws + 50331648);
    float* pmin = (float*)(ws + 50397184);
    int*   pid  = (int*)  (ws + 50659328);

    nn_prep<<<10240, 256, 0, stream>>>(x, codes, xh, xl, chh, cll, c2);
    nn_gemm<<<32 * NCHUNK, 512, 0, stream>>>(xh, xl, chh, cll, c2, pmin, pid);
    nn_fin<<<NTOK / 4, 256, 0, stream>>>(x, pmin, pid, out);
}